// Round 10
// baseline (109.325 us; speedup 1.0000x reference)
//
#include <hip/hip_runtime.h>
#include <math.h>

#define BB 8
#define SS 4096
#define EE 128
#define HH 64
#define NT 16   // KV tiles per flash block (split-K4: 1024 keys / 64)
#define LOG2E 1.44269504088896f

typedef _Float16 f16;
typedef __attribute__((ext_vector_type(8))) _Float16 f16x8;
typedef __attribute__((ext_vector_type(4))) float f32x4;
typedef __attribute__((ext_vector_type(16))) float f32x16;
typedef __attribute__((ext_vector_type(4))) unsigned int u32x4;

__device__ __forceinline__ unsigned int pk2h(float a, float b) {
    return __builtin_bit_cast(unsigned int, __builtin_amdgcn_cvt_pkrtz(a, b));
}

// async global->LDS DMA, 16 B per lane (linear LDS dest; swizzle is applied
// to the per-lane GLOBAL source address -- m173 pattern / rule #21).
__device__ __forceinline__ void async_copy16(void* lds, const void* g) {
    __builtin_amdgcn_global_load_lds(
        (const __attribute__((address_space(1))) void*)g,
        (__attribute__((address_space(3))) void*)lds, 16, 0, 0);
}

// ALL-WAVES buffer handoff: per-wave vmcnt(0)+lgkmcnt(0) then s_barrier.
// vmcnt is per-wave; the s_barrier is what makes every wave's DMA chunk
// visible to every reader (R7's race: dropping the barrier here).
__device__ __forceinline__ void vm_barrier() {
    asm volatile("s_waitcnt vmcnt(0) lgkmcnt(0)" ::: "memory");
    __builtin_amdgcn_s_barrier();
    __builtin_amdgcn_sched_barrier(0);
}

// ---------------- W transpose+convert setup ----------------
// Wt f16 [192 cols][128 e]: cols 0-63 = Wq*log2e, 64-127 = Wk, 128-191 = Wv.
__global__ __launch_bounds__(256) void wtrans_kernel(
    const float* __restrict__ Wq, const float* __restrict__ Wk,
    const float* __restrict__ Wv, f16* __restrict__ Wt)
{
    const int idx = blockIdx.x * 256 + threadIdx.x;
    if (idx >= 192 * 128) return;
    const int col = idx >> 7, e = idx & 127;
    const float v = (col < 64)  ? Wq[e * 64 + col] * LOG2E
                  : (col < 128) ? Wk[e * 64 + (col - 64)]
                                : Wv[e * 64 + (col - 128)];
    Wt[col * 128 + e] = (f16)v;
}

// ---------------- QKV projection: fp16 MFMA GEMM, no LDS ----------------
// A-frags read directly from global x (coalesced, L2-backed). Q pre-scaled
// by log2e. Vt written with sigma-permuted key index (swap bits 2<->3 of the
// low nibble) so flash PV fragments are single b128 reads.
__global__ __launch_bounds__(256) void qkv_kernel(
    const float* __restrict__ x, const f16* __restrict__ Wt,
    const float* __restrict__ bq, const float* __restrict__ bk,
    const float* __restrict__ bv,
    f16* __restrict__ Q, f16* __restrict__ K, f16* __restrict__ Vt)
{
    const int tid  = threadIdx.x;
    const int lane = tid & 63;
    const int wid  = tid >> 6;
    const int ln15 = lane & 15;
    const int lg   = lane >> 4;
    const long rowbase = (long)blockIdx.x * 64;

    // A fragments: row = wid*16 + ln15, dim = s*32 + lg*8 + j
    f16x8 xa[4];
    {
        const float* xp = x + (rowbase + wid * 16 + ln15) * EE + lg * 8;
#pragma unroll
        for (int s = 0; s < 4; ++s) {
            const float4 u = *(const float4*)(xp + s * 32);
            const float4 v = *(const float4*)(xp + s * 32 + 4);
            const u32x4 w = {pk2h(u.x, u.y), pk2h(u.z, u.w),
                             pk2h(v.x, v.y), pk2h(v.z, v.w)};
            xa[s] = __builtin_bit_cast(f16x8, w);
        }
    }

    f32x4 acc[12];
#pragma unroll
    for (int ct = 0; ct < 12; ++ct) acc[ct] = (f32x4){0.f, 0.f, 0.f, 0.f};

#pragma unroll
    for (int ct = 0; ct < 12; ++ct) {
        const f16* wtp = Wt + (ct * 16 + ln15) * 128 + lg * 8;
#pragma unroll
        for (int s = 0; s < 4; ++s) {
            const f16x8 wb = *(const f16x8*)(wtp + s * 32);
            acc[ct] = __builtin_amdgcn_mfma_f32_16x16x32_f16(xa[s], wb, acc[ct], 0, 0, 0);
        }
    }

    const long grow0 = rowbase + wid * 16 + 4 * lg;
#pragma unroll
    for (int ct = 0; ct < 4; ++ct) {
        const int col = ct * 16 + ln15;
        const float b = bq[col] * LOG2E;
#pragma unroll
        for (int r = 0; r < 4; ++r)
            Q[(grow0 + r) * HH + col] = (f16)(acc[ct][r] + b);
    }
#pragma unroll
    for (int ct = 4; ct < 8; ++ct) {
        const int col = (ct - 4) * 16 + ln15;
        const float b = bk[col];
#pragma unroll
        for (int r = 0; r < 4; ++r)
            K[(grow0 + r) * HH + col] = (f16)(acc[ct][r] + b);
    }
    {
        const long batch = rowbase >> 12;
        // sigma-permuted key index: key&15 = 4*lg + r -> pos&15 = 8*(lg&1)+4*(lg>>1)+r
        const long inrow0 = (rowbase & 4095) + wid * 16;
        const long inrowP = inrow0 + 8 * (lg & 1) + 4 * (lg >> 1);
#pragma unroll
        for (int ct = 8; ct < 12; ++ct) {
            const int o = (ct - 8) * 16 + ln15;
            const float b = bv[o];
            unsigned long long pk =
                (unsigned long long)pk2h(acc[ct][0] + b, acc[ct][1] + b) |
                ((unsigned long long)pk2h(acc[ct][2] + b, acc[ct][3] + b) << 32);
            *(unsigned long long*)(Vt + ((long)batch * HH + o) * SS + inrowP) = pk;
        }
    }
}

// ---------------- MFMA flash attention, 32x32, O^T, score-prefetch ----------------
// grid 1024 = 8 batch (XCD-affine) x 4 split x 32 qblk; 256 thr = 4 waves.
// Wave = 32 q rows (q = lane&31). KV tile = 64 keys. Phase-offset pipeline:
// per iter: issue K(t+2)/V(t+1) DMA -> qkt(t+1) [independent MFMA, overlaps
// softmax(t) VALU] -> smpv(t) -> vm_barrier (ONE all-waves barrier/tile;
// every DMA drains at the barrier ending its issuing iteration, cover =
// full tile compute). Buffer-liveness: each DMA target was last read before
// the PRECEDING barrier. P in registers; sigma-permuted Vt -> b128 PV reads.
__global__ __launch_bounds__(256, 4) void flash_kernel(
    const f16* __restrict__ Q, const f16* __restrict__ K,
    const f16* __restrict__ Vt, f16* __restrict__ Onorm,
    float* __restrict__ lse)
{
    __shared__ __align__(16) short k_s[2][64 * HH];   // 2 x 8 KB
    __shared__ __align__(16) short v_s[2][64 * HH];   // 2 x 8 KB  [o][key-perm]

    const int tid  = threadIdx.x;
    const int lane = tid & 63;
    const int wid  = tid >> 6;
    const int q31  = lane & 31;
    const int h5   = lane >> 5;
    const int batch = blockIdx.x & 7;
    const int split = (blockIdx.x >> 3) & 3;
    const int qblk  = blockIdx.x >> 5;
    const int k0base = split * (SS / 4);

    // Q B-frags: col q = q31, k-slot 8h5+j at dim 16*step + 8*h5 + j
    f16x8 qf[4];
    {
        const long qrow = (long)batch * SS + qblk * 128 + wid * 32 + q31;
        const f16* qp = Q + qrow * HH + 8 * h5;
        qf[0] = *(const f16x8*)(qp);
        qf[1] = *(const f16x8*)(qp + 16);
        qf[2] = *(const f16x8*)(qp + 32);
        qf[3] = *(const f16x8*)(qp + 48);
    }

    f32x16 oacc0 = {0.f,0.f,0.f,0.f,0.f,0.f,0.f,0.f,0.f,0.f,0.f,0.f,0.f,0.f,0.f,0.f};
    f32x16 oacc1 = oacc0;           // O^T rows o (+32), col q = q31
    float m = -1e30f, l = 0.f;

    // ---- DMA staging geometry ----
    const int crow = lane >> 3;                       // 0..7
    const int ccs  = ((lane & 7) * 16) ^ (crow << 4); // swizzled col bytes
    const int row0 = wid * 16 + crow;                 // rows row0, row0+8
    const char* kgb = (const char*)(K + ((long)batch * SS + k0base) * HH);
    const char* vgb = (const char*)(Vt + (long)batch * HH * SS);
    const long koff = (long)row0 * 128 + ccs;
    const long voff = (long)row0 * (SS * 2) + k0base * 2 + ccs;

    auto issue_k = [&](int t, int b) __attribute__((always_inline)) {
        char* kl = (char*)k_s[b] + wid * 2048;
        const char* kg = kgb + (long)t * (64 * 128) + koff;
        async_copy16(kl,        kg);
        async_copy16(kl + 1024, kg + 1024);            // rows +8
    };
    auto issue_v = [&](int t, int b) __attribute__((always_inline)) {
        char* vl = (char*)v_s[b] + wid * 2048;
        const char* vg = vgb + (long)t * 128 + voff;
        async_copy16(vl,        vg);
        async_copy16(vl + 1024, vg + 8 * (SS * 2));    // rows +8
    };

    // S^T[key][q] = mfma(A=K rows, B=Q cols), log2 domain
    auto qkt = [&](const short* ksp, f32x16& s0, f32x16& s1)
        __attribute__((always_inline)) {
        const char* ks = (const char*)ksp;
        s0 = (f32x16){0.f,0.f,0.f,0.f,0.f,0.f,0.f,0.f,0.f,0.f,0.f,0.f,0.f,0.f,0.f,0.f};
        s1 = s0;
        __builtin_amdgcn_s_setprio(1);
#pragma unroll
        for (int step = 0; step < 4; ++step) {
            const int cb = step * 32 + 16 * h5;
            const int r0 = q31;
            const f16x8 ka0 = *(const f16x8*)(ks + ((r0 * 128 + cb) ^ ((r0 & 7) << 4)));
            s0 = __builtin_amdgcn_mfma_f32_32x32x16_f16(ka0, qf[step], s0, 0, 0, 0);
            const int r1 = q31 + 32;
            const f16x8 ka1 = *(const f16x8*)(ks + ((r1 * 128 + cb) ^ ((r1 & 7) << 4)));
            s1 = __builtin_amdgcn_mfma_f32_32x32x16_f16(ka1, qf[step], s1, 0, 0, 0);
        }
        __builtin_amdgcn_s_setprio(0);
    };

    // online softmax (exp2 domain, defer-max, max3 chains) + O^T += V^T.P
    auto smpv = [&](f32x16& s0, f32x16& s1, const short* vsp)
        __attribute__((always_inline)) {
        const char* vs = (const char*)vsp;
        // 4 independent max3-fusable chains (T17), then combine
        float c0 = fmaxf(fmaxf(s0[0], s0[1]), s0[2]);
        c0 = fmaxf(fmaxf(c0, s0[3]), s0[4]);
        c0 = fmaxf(fmaxf(c0, s0[5]), s0[6]);
        float c1 = fmaxf(fmaxf(s0[8], s0[9]), s0[10]);
        c1 = fmaxf(fmaxf(c1, s0[11]), s0[12]);
        c1 = fmaxf(fmaxf(c1, s0[13]), s0[14]);
        float c2 = fmaxf(fmaxf(s1[0], s1[1]), s1[2]);
        c2 = fmaxf(fmaxf(c2, s1[3]), s1[4]);
        c2 = fmaxf(fmaxf(c2, s1[5]), s1[6]);
        float c3 = fmaxf(fmaxf(s1[8], s1[9]), s1[10]);
        c3 = fmaxf(fmaxf(c3, s1[11]), s1[12]);
        c3 = fmaxf(fmaxf(c3, s1[13]), s1[14]);
        c0 = fmaxf(fmaxf(c0, s0[7]), s0[15]);
        c2 = fmaxf(fmaxf(c2, s1[7]), s1[15]);
        float tm = fmaxf(fmaxf(c0, c1), fmaxf(c2, c3));
        tm = fmaxf(tm, __shfl_xor(tm, 32));
        if (!__all(tm <= m + 11.5f)) {
            const float mn = fmaxf(m, tm);
            const float alpha = __builtin_amdgcn_exp2f(m - mn);
            l *= alpha;
            oacc0 *= alpha;              // lane-local: O^T col = q
            oacc1 *= alpha;
            m = mn;
        }

        unsigned int pk[16];
        float ps = 0.f;
#pragma unroll
        for (int i = 0; i < 8; ++i) {
            const float a = __builtin_amdgcn_exp2f(s0[2 * i] - m);
            const float b = __builtin_amdgcn_exp2f(s0[2 * i + 1] - m);
            ps += a + b;
            pk[i] = pk2h(a, b);
        }
#pragma unroll
        for (int i = 0; i < 8; ++i) {
            const float a = __builtin_amdgcn_exp2f(s1[2 * i] - m);
            const float b = __builtin_amdgcn_exp2f(s1[2 * i + 1] - m);
            ps += a + b;
            pk[8 + i] = pk2h(a, b);
        }
        ps += __shfl_xor(ps, 32);
        l += ps;

        // ---- O^T += V^T . P  (A = V^T single b128, sigma-permuted; B = P regs) ----
        __builtin_amdgcn_s_setprio(1);
#pragma unroll
        for (int mb = 0; mb < 4; ++mb) {
            const u32x4 pw = {pk[4 * mb], pk[4 * mb + 1], pk[4 * mb + 2], pk[4 * mb + 3]};
            const f16x8 pb = __builtin_bit_cast(f16x8, pw);
            const int cb = 32 * mb + 16 * h5;
#pragma unroll
            for (int oh = 0; oh < 2; ++oh) {
                const int row = q31 + 32 * oh;
                const f16x8 va = *(const f16x8*)(vs + ((row * 128 + cb) ^ ((row & 7) << 4)));
                if (oh == 0)
                    oacc0 = __builtin_amdgcn_mfma_f32_32x32x16_f16(va, pb, oacc0, 0, 0, 0);
                else
                    oacc1 = __builtin_amdgcn_mfma_f32_32x32x16_f16(va, pb, oacc1, 0, 0, 0);
            }
        }
        __builtin_amdgcn_s_setprio(0);
    };

    f32x16 sA0, sA1, sB0, sB1;

    // prologue: K0,V0 -> buf0 (drained); K1 -> kb1; scores(0); drain K1
    issue_k(0, 0);
    issue_v(0, 0);
    vm_barrier();
    issue_k(1, 1);
    qkt(k_s[0], sA0, sA1);
    vm_barrier();

    for (int t = 0; t < NT; t += 2) {
        // phase A: tile t (even). kb0's K(t) / vb1's V(t-1) dead pre-barrier.
        if (t + 2 < NT) issue_k(t + 2, 0);
        issue_v(t + 1, 1);
        qkt(k_s[1], sB0, sB1);               // scores(t+1), independent of smpv(t)
        smpv(sA0, sA1, v_s[0]);
        vm_barrier();
        // phase B: tile t+1 (odd). kb1's K(t+1) / vb0's V(t) dead pre-barrier.
        if (t + 3 < NT) issue_k(t + 3, 1);
        if (t + 2 < NT) issue_v(t + 2, 0);
        if (t + 2 < NT) qkt(k_s[0], sA0, sA1);
        smpv(sB0, sB1, v_s[1]);
        vm_barrier();
    }

    // epilogue: normalized f16 partials (O^T scatter) + log2-LSE
    const float linv = 1.0f / l;
    const long tok = (long)split * (BB * SS) + (long)batch * SS + qblk * 128 + wid * 32 + q31;
    f16* ob = Onorm + tok * HH;
#pragma unroll
    for (int i = 0; i < 16; ++i) {
        const int od = (i & 3) + 8 * (i >> 2) + 4 * h5;
        ob[od]      = (f16)(oacc0[i] * linv);
        ob[od + 32] = (f16)(oacc1[i] * linv);
    }
    if (h5 == 0)
        lse[tok] = m + __builtin_amdgcn_logf(l);
}

// ---------------- split-K merge (log2-LSE weighted) ----------------
__global__ __launch_bounds__(256) void merge_kernel(
    const f16* __restrict__ Onorm, const float* __restrict__ lse,
    float* __restrict__ Out)
{
    const int gid = blockIdx.x * 256 + threadIdx.x;   // 32768 rows x 8 col-groups
    const long row = gid >> 3;
    const int c0 = (gid & 7) * 8;
    const long NR = (long)BB * SS;

    float ls[4];
#pragma unroll
    for (int i = 0; i < 4; ++i) ls[i] = lse[i * NR + row];
    const float M = fmaxf(fmaxf(ls[0], ls[1]), fmaxf(ls[2], ls[3]));
    float g[4], denom = 0.f;
#pragma unroll
    for (int i = 0; i < 4; ++i) { g[i] = __builtin_amdgcn_exp2f(ls[i] - M); denom += g[i]; }
    const float inv = 1.0f / denom;

    float acc[8];
#pragma unroll
    for (int j = 0; j < 8; ++j) acc[j] = 0.f;
#pragma unroll
    for (int i = 0; i < 4; ++i) {
        const f16x8 o = *(const f16x8*)(Onorm + (i * NR + row) * HH + c0);
#pragma unroll
        for (int j = 0; j < 8; ++j) acc[j] = fmaf(g[i], (float)o[j], acc[j]);
    }
    float4 r0, r1;
    r0.x = acc[0] * inv; r0.y = acc[1] * inv; r0.z = acc[2] * inv; r0.w = acc[3] * inv;
    r1.x = acc[4] * inv; r1.y = acc[5] * inv; r1.z = acc[6] * inv; r1.w = acc[7] * inv;
    float4* dst = (float4*)(Out + row * HH + c0);
    dst[0] = r0;
    dst[1] = r1;
}

extern "C" void kernel_launch(void* const* d_in, const int* in_sizes, int n_in,
                              void* d_out, int out_size, void* d_ws, size_t ws_size,
                              hipStream_t stream) {
    const float* x  = (const float*)d_in[0];
    const float* Wq = (const float*)d_in[1];
    const float* bq = (const float*)d_in[2];
    const float* Wk = (const float*)d_in[3];
    const float* bk = (const float*)d_in[4];
    const float* Wv = (const float*)d_in[5];
    const float* bv = (const float*)d_in[6];
    float* out = (float*)d_out;

    // ws: Q f16 4MB | K f16 4MB | Vt f16 4MB | Wt 48KB | Onorm f16 16MB | lse f32 512KB
    const size_t NTOK = (size_t)BB * SS;
    f16* Q  = (f16*)d_ws;
    f16* K  = Q + NTOK * HH;
    f16* Vt = K + NTOK * HH;
    f16* Wt = Vt + NTOK * HH;
    f16* Onorm = Wt + 192 * 128;
    float* lse = (float*)(Onorm + 4 * NTOK * HH);

    wtrans_kernel<<<96, 256, 0, stream>>>(Wq, Wk, Wv, Wt);
    qkv_kernel<<<BB * SS / 64, 256, 0, stream>>>(x, Wt, bq, bk, bv, Q, K, Vt);
    flash_kernel<<<BB * 4 * (SS / 128), 256, 0, stream>>>(Q, K, Vt, Onorm, lse);
    merge_kernel<<<BB * SS * 8 / 256, 256, 0, stream>>>(Onorm, lse, out);
}

// Round 11
// 86.629 us; speedup vs baseline: 1.2620x; 1.2620x over previous
//
#include <hip/hip_runtime.h>
#include <math.h>

#define BB 8
#define SS 4096
#define EE 128
#define HH 64
#define NT 16   // KV tiles per flash block (split-K4: 1024 keys / 64)
#define LOG2E 1.44269504088896f

typedef _Float16 f16;
typedef __attribute__((ext_vector_type(8))) _Float16 f16x8;
typedef __attribute__((ext_vector_type(4))) float f32x4;
typedef __attribute__((ext_vector_type(16))) float f32x16;
typedef __attribute__((ext_vector_type(4))) unsigned int u32x4;

__device__ __forceinline__ unsigned int pk2h(float a, float b) {
    return __builtin_bit_cast(unsigned int, __builtin_amdgcn_cvt_pkrtz(a, b));
}

// async global->LDS DMA, 16 B per lane (linear LDS dest; swizzle is applied
// to the per-lane GLOBAL source address -- m173 pattern / rule #21).
__device__ __forceinline__ void async_copy16(void* lds, const void* g) {
    __builtin_amdgcn_global_load_lds(
        (const __attribute__((address_space(1))) void*)g,
        (__attribute__((address_space(3))) void*)lds, 16, 0, 0);
}

// ALL-WAVES buffer handoff: per-wave vmcnt(0)+lgkmcnt(0) then s_barrier.
// vmcnt is per-wave; the s_barrier is what makes every wave's DMA chunk
// visible to every reader (R7's race: dropping the barrier here).
__device__ __forceinline__ void vm_barrier() {
    asm volatile("s_waitcnt vmcnt(0) lgkmcnt(0)" ::: "memory");
    __builtin_amdgcn_s_barrier();
    __builtin_amdgcn_sched_barrier(0);
}

// ---------------- W transpose+convert setup ----------------
// Wt f16 [192 cols][128 e]: cols 0-63 = Wq*log2e, 64-127 = Wk, 128-191 = Wv.
__global__ __launch_bounds__(256) void wtrans_kernel(
    const float* __restrict__ Wq, const float* __restrict__ Wk,
    const float* __restrict__ Wv, f16* __restrict__ Wt)
{
    const int idx = blockIdx.x * 256 + threadIdx.x;
    if (idx >= 192 * 128) return;
    const int col = idx >> 7, e = idx & 127;
    const float v = (col < 64)  ? Wq[e * 64 + col] * LOG2E
                  : (col < 128) ? Wk[e * 64 + (col - 64)]
                                : Wv[e * 64 + (col - 128)];
    Wt[col * 128 + e] = (f16)v;
}

// ---------------- QKV projection: fp16 MFMA GEMM, no LDS ----------------
// A-frags read directly from global x (coalesced, L2-backed). Q pre-scaled
// by log2e. Vt written with sigma-permuted key index (swap bits 2<->3 of the
// low nibble) so flash PV fragments are single b128 reads.
__global__ __launch_bounds__(256) void qkv_kernel(
    const float* __restrict__ x, const f16* __restrict__ Wt,
    const float* __restrict__ bq, const float* __restrict__ bk,
    const float* __restrict__ bv,
    f16* __restrict__ Q, f16* __restrict__ K, f16* __restrict__ Vt)
{
    const int tid  = threadIdx.x;
    const int lane = tid & 63;
    const int wid  = tid >> 6;
    const int ln15 = lane & 15;
    const int lg   = lane >> 4;
    const long rowbase = (long)blockIdx.x * 64;

    // A fragments: row = wid*16 + ln15, dim = s*32 + lg*8 + j
    f16x8 xa[4];
    {
        const float* xp = x + (rowbase + wid * 16 + ln15) * EE + lg * 8;
#pragma unroll
        for (int s = 0; s < 4; ++s) {
            const float4 u = *(const float4*)(xp + s * 32);
            const float4 v = *(const float4*)(xp + s * 32 + 4);
            const u32x4 w = {pk2h(u.x, u.y), pk2h(u.z, u.w),
                             pk2h(v.x, v.y), pk2h(v.z, v.w)};
            xa[s] = __builtin_bit_cast(f16x8, w);
        }
    }

    f32x4 acc[12];
#pragma unroll
    for (int ct = 0; ct < 12; ++ct) acc[ct] = (f32x4){0.f, 0.f, 0.f, 0.f};

#pragma unroll
    for (int ct = 0; ct < 12; ++ct) {
        const f16* wtp = Wt + (ct * 16 + ln15) * 128 + lg * 8;
#pragma unroll
        for (int s = 0; s < 4; ++s) {
            const f16x8 wb = *(const f16x8*)(wtp + s * 32);
            acc[ct] = __builtin_amdgcn_mfma_f32_16x16x32_f16(xa[s], wb, acc[ct], 0, 0, 0);
        }
    }

    const long grow0 = rowbase + wid * 16 + 4 * lg;
#pragma unroll
    for (int ct = 0; ct < 4; ++ct) {
        const int col = ct * 16 + ln15;
        const float b = bq[col] * LOG2E;
#pragma unroll
        for (int r = 0; r < 4; ++r)
            Q[(grow0 + r) * HH + col] = (f16)(acc[ct][r] + b);
    }
#pragma unroll
    for (int ct = 4; ct < 8; ++ct) {
        const int col = (ct - 4) * 16 + ln15;
        const float b = bk[col];
#pragma unroll
        for (int r = 0; r < 4; ++r)
            K[(grow0 + r) * HH + col] = (f16)(acc[ct][r] + b);
    }
    {
        const long batch = rowbase >> 12;
        // sigma-permuted key index: key&15 = 4*lg + r -> pos&15 = 8*(lg&1)+4*(lg>>1)+r
        const long inrow0 = (rowbase & 4095) + wid * 16;
        const long inrowP = inrow0 + 8 * (lg & 1) + 4 * (lg >> 1);
#pragma unroll
        for (int ct = 8; ct < 12; ++ct) {
            const int o = (ct - 8) * 16 + ln15;
            const float b = bv[o];
            unsigned long long pk =
                (unsigned long long)pk2h(acc[ct][0] + b, acc[ct][1] + b) |
                ((unsigned long long)pk2h(acc[ct][2] + b, acc[ct][3] + b) << 32);
            *(unsigned long long*)(Vt + ((long)batch * HH + o) * SS + inrowP) = pk;
        }
    }
}

// ---------------- MFMA flash attention, 32x32, O^T, score-prefetch ----------------
// grid 1024 = 8 batch (XCD-affine) x 4 split x 32 qblk; 256 thr = 4 waves.
// Wave = 32 q rows (q = lane&31). KV tile = 64 keys. Phase-offset pipeline:
// per iter: issue K(t+2)/V(t+1) DMA -> qkt(t+1) [independent MFMA, overlaps
// softmax(t) VALU] -> smpv(t) -> vm_barrier (ONE all-waves barrier/tile).
// launch_bounds(256,3): alloc cap ~170 VGPR so the ~135-reg live set does
// NOT spill (R9: the (256,4)=128 cap caused hot-loop spills, FETCH 44MB).
// smpv fuses exp2->pack->PV per 16-key group: lower liveness + TRANS ops
// issue under the MFMA shadow.
__global__ __launch_bounds__(256, 3) void flash_kernel(
    const f16* __restrict__ Q, const f16* __restrict__ K,
    const f16* __restrict__ Vt, f16* __restrict__ Onorm,
    float* __restrict__ lse)
{
    __shared__ __align__(16) short k_s[2][64 * HH];   // 2 x 8 KB
    __shared__ __align__(16) short v_s[2][64 * HH];   // 2 x 8 KB  [o][key-perm]

    const int tid  = threadIdx.x;
    const int lane = tid & 63;
    const int wid  = tid >> 6;
    const int q31  = lane & 31;
    const int h5   = lane >> 5;
    const int batch = blockIdx.x & 7;
    const int split = (blockIdx.x >> 3) & 3;
    const int qblk  = blockIdx.x >> 5;
    const int k0base = split * (SS / 4);

    // Q B-frags: col q = q31, k-slot 8h5+j at dim 16*step + 8*h5 + j
    f16x8 qf[4];
    {
        const long qrow = (long)batch * SS + qblk * 128 + wid * 32 + q31;
        const f16* qp = Q + qrow * HH + 8 * h5;
        qf[0] = *(const f16x8*)(qp);
        qf[1] = *(const f16x8*)(qp + 16);
        qf[2] = *(const f16x8*)(qp + 32);
        qf[3] = *(const f16x8*)(qp + 48);
    }

    f32x16 oacc0 = {0.f,0.f,0.f,0.f,0.f,0.f,0.f,0.f,0.f,0.f,0.f,0.f,0.f,0.f,0.f,0.f};
    f32x16 oacc1 = oacc0;           // O^T rows o (+32), col q = q31
    float m = -1e30f, l = 0.f;

    // ---- DMA staging geometry ----
    const int crow = lane >> 3;                       // 0..7
    const int ccs  = ((lane & 7) * 16) ^ (crow << 4); // swizzled col bytes
    const int row0 = wid * 16 + crow;                 // rows row0, row0+8
    const char* kgb = (const char*)(K + ((long)batch * SS + k0base) * HH);
    const char* vgb = (const char*)(Vt + (long)batch * HH * SS);
    const long koff = (long)row0 * 128 + ccs;
    const long voff = (long)row0 * (SS * 2) + k0base * 2 + ccs;

    auto issue_k = [&](int t, int b) __attribute__((always_inline)) {
        char* kl = (char*)k_s[b] + wid * 2048;
        const char* kg = kgb + (long)t * (64 * 128) + koff;
        async_copy16(kl,        kg);
        async_copy16(kl + 1024, kg + 1024);            // rows +8
    };
    auto issue_v = [&](int t, int b) __attribute__((always_inline)) {
        char* vl = (char*)v_s[b] + wid * 2048;
        const char* vg = vgb + (long)t * 128 + voff;
        async_copy16(vl,        vg);
        async_copy16(vl + 1024, vg + 8 * (SS * 2));    // rows +8
    };

    // S^T[key][q] = mfma(A=K rows, B=Q cols), log2 domain
    auto qkt = [&](const short* ksp, f32x16& s0, f32x16& s1)
        __attribute__((always_inline)) {
        const char* ks = (const char*)ksp;
        s0 = (f32x16){0.f,0.f,0.f,0.f,0.f,0.f,0.f,0.f,0.f,0.f,0.f,0.f,0.f,0.f,0.f,0.f};
        s1 = s0;
        __builtin_amdgcn_s_setprio(1);
#pragma unroll
        for (int step = 0; step < 4; ++step) {
            const int cb = step * 32 + 16 * h5;
            const int r0 = q31;
            const f16x8 ka0 = *(const f16x8*)(ks + ((r0 * 128 + cb) ^ ((r0 & 7) << 4)));
            s0 = __builtin_amdgcn_mfma_f32_32x32x16_f16(ka0, qf[step], s0, 0, 0, 0);
            const int r1 = q31 + 32;
            const f16x8 ka1 = *(const f16x8*)(ks + ((r1 * 128 + cb) ^ ((r1 & 7) << 4)));
            s1 = __builtin_amdgcn_mfma_f32_32x32x16_f16(ka1, qf[step], s1, 0, 0, 0);
        }
        __builtin_amdgcn_s_setprio(0);
    };

    // online softmax (exp2 domain, defer-max, max3 chains) with the
    // exp2->pack->PV pipeline fused per 16-key group.
    auto smpv = [&](f32x16& s0, f32x16& s1, const short* vsp)
        __attribute__((always_inline)) {
        const char* vs = (const char*)vsp;
        // 4 independent max3-fusable chains (T17), then combine
        float c0 = fmaxf(fmaxf(s0[0], s0[1]), s0[2]);
        c0 = fmaxf(fmaxf(c0, s0[3]), s0[4]);
        c0 = fmaxf(fmaxf(c0, s0[5]), s0[6]);
        float c1 = fmaxf(fmaxf(s0[8], s0[9]), s0[10]);
        c1 = fmaxf(fmaxf(c1, s0[11]), s0[12]);
        c1 = fmaxf(fmaxf(c1, s0[13]), s0[14]);
        float c2 = fmaxf(fmaxf(s1[0], s1[1]), s1[2]);
        c2 = fmaxf(fmaxf(c2, s1[3]), s1[4]);
        c2 = fmaxf(fmaxf(c2, s1[5]), s1[6]);
        float c3 = fmaxf(fmaxf(s1[8], s1[9]), s1[10]);
        c3 = fmaxf(fmaxf(c3, s1[11]), s1[12]);
        c3 = fmaxf(fmaxf(c3, s1[13]), s1[14]);
        c0 = fmaxf(fmaxf(c0, s0[7]), s0[15]);
        c2 = fmaxf(fmaxf(c2, s1[7]), s1[15]);
        float tm = fmaxf(fmaxf(c0, c1), fmaxf(c2, c3));
        tm = fmaxf(tm, __shfl_xor(tm, 32));
        if (!__all(tm <= m + 11.5f)) {
            const float mn = fmaxf(m, tm);
            const float alpha = __builtin_amdgcn_exp2f(m - mn);
            l *= alpha;
            oacc0 *= alpha;              // lane-local: O^T col = q
            oacc1 *= alpha;
            m = mn;
        }

        float ps = 0.f;
        __builtin_amdgcn_s_setprio(1);
#pragma unroll
        for (int mb = 0; mb < 4; ++mb) {
            // 8 exp2 + 4 packs for this 16-key group (issues under MFMA shadow)
            float e[8];
#pragma unroll
            for (int j = 0; j < 8; ++j) {
                const float sv = (mb < 2) ? s0[(mb & 1) * 8 + j] : s1[(mb & 1) * 8 + j];
                e[j] = __builtin_amdgcn_exp2f(sv - m);
                ps += e[j];
            }
            const u32x4 pw = {pk2h(e[0], e[1]), pk2h(e[2], e[3]),
                              pk2h(e[4], e[5]), pk2h(e[6], e[7])};
            const f16x8 pb = __builtin_bit_cast(f16x8, pw);
            const int cb = 32 * mb + 16 * h5;
#pragma unroll
            for (int oh = 0; oh < 2; ++oh) {
                const int row = q31 + 32 * oh;
                const f16x8 va = *(const f16x8*)(vs + ((row * 128 + cb) ^ ((row & 7) << 4)));
                if (oh == 0)
                    oacc0 = __builtin_amdgcn_mfma_f32_32x32x16_f16(va, pb, oacc0, 0, 0, 0);
                else
                    oacc1 = __builtin_amdgcn_mfma_f32_32x32x16_f16(va, pb, oacc1, 0, 0, 0);
            }
        }
        __builtin_amdgcn_s_setprio(0);
        ps += __shfl_xor(ps, 32);
        l += ps;
    };

    f32x16 sA0, sA1, sB0, sB1;

    // prologue: K0,V0 -> buf0 (drained); K1 -> kb1; scores(0); drain K1
    issue_k(0, 0);
    issue_v(0, 0);
    vm_barrier();
    issue_k(1, 1);
    qkt(k_s[0], sA0, sA1);
    vm_barrier();

    for (int t = 0; t < NT; t += 2) {
        // phase A: tile t (even). kb0's K(t) / vb1's V(t-1) dead pre-barrier.
        if (t + 2 < NT) issue_k(t + 2, 0);
        issue_v(t + 1, 1);
        qkt(k_s[1], sB0, sB1);               // scores(t+1), independent of smpv(t)
        smpv(sA0, sA1, v_s[0]);
        vm_barrier();
        // phase B: tile t+1 (odd). kb1's K(t+1) / vb0's V(t) dead pre-barrier.
        if (t + 3 < NT) issue_k(t + 3, 1);
        if (t + 2 < NT) issue_v(t + 2, 0);
        if (t + 2 < NT) qkt(k_s[0], sA0, sA1);
        smpv(sB0, sB1, v_s[1]);
        vm_barrier();
    }

    // epilogue: normalized f16 partials (O^T scatter) + log2-LSE
    const float linv = 1.0f / l;
    const long tok = (long)split * (BB * SS) + (long)batch * SS + qblk * 128 + wid * 32 + q31;
    f16* ob = Onorm + tok * HH;
#pragma unroll
    for (int i = 0; i < 16; ++i) {
        const int od = (i & 3) + 8 * (i >> 2) + 4 * h5;
        ob[od]      = (f16)(oacc0[i] * linv);
        ob[od + 32] = (f16)(oacc1[i] * linv);
    }
    if (h5 == 0)
        lse[tok] = m + __builtin_amdgcn_logf(l);
}

// ---------------- split-K merge (log2-LSE weighted) ----------------
__global__ __launch_bounds__(256) void merge_kernel(
    const f16* __restrict__ Onorm, const float* __restrict__ lse,
    float* __restrict__ Out)
{
    const int gid = blockIdx.x * 256 + threadIdx.x;   // 32768 rows x 8 col-groups
    const long row = gid >> 3;
    const int c0 = (gid & 7) * 8;
    const long NR = (long)BB * SS;

    float ls[4];
#pragma unroll
    for (int i = 0; i < 4; ++i) ls[i] = lse[i * NR + row];
    const float M = fmaxf(fmaxf(ls[0], ls[1]), fmaxf(ls[2], ls[3]));
    float g[4], denom = 0.f;
#pragma unroll
    for (int i = 0; i < 4; ++i) { g[i] = __builtin_amdgcn_exp2f(ls[i] - M); denom += g[i]; }
    const float inv = 1.0f / denom;

    float acc[8];
#pragma unroll
    for (int j = 0; j < 8; ++j) acc[j] = 0.f;
#pragma unroll
    for (int i = 0; i < 4; ++i) {
        const f16x8 o = *(const f16x8*)(Onorm + (i * NR + row) * HH + c0);
#pragma unroll
        for (int j = 0; j < 8; ++j) acc[j] = fmaf(g[i], (float)o[j], acc[j]);
    }
    float4 r0, r1;
    r0.x = acc[0] * inv; r0.y = acc[1] * inv; r0.z = acc[2] * inv; r0.w = acc[3] * inv;
    r1.x = acc[4] * inv; r1.y = acc[5] * inv; r1.z = acc[6] * inv; r1.w = acc[7] * inv;
    float4* dst = (float4*)(Out + row * HH + c0);
    dst[0] = r0;
    dst[1] = r1;
}

extern "C" void kernel_launch(void* const* d_in, const int* in_sizes, int n_in,
                              void* d_out, int out_size, void* d_ws, size_t ws_size,
                              hipStream_t stream) {
    const float* x  = (const float*)d_in[0];
    const float* Wq = (const float*)d_in[1];
    const float* bq = (const float*)d_in[2];
    const float* Wk = (const float*)d_in[3];
    const float* bk = (const float*)d_in[4];
    const float* Wv = (const float*)d_in[5];
    const float* bv = (const float*)d_in[6];
    float* out = (float*)d_out;

    // ws: Q f16 4MB | K f16 4MB | Vt f16 4MB | Wt 48KB | Onorm f16 16MB | lse f32 512KB
    const size_t NTOK = (size_t)BB * SS;
    f16* Q  = (f16*)d_ws;
    f16* K  = Q + NTOK * HH;
    f16* Vt = K + NTOK * HH;
    f16* Wt = Vt + NTOK * HH;
    f16* Onorm = Wt + 192 * 128;
    float* lse = (float*)(Onorm + 4 * NTOK * HH);

    wtrans_kernel<<<96, 256, 0, stream>>>(Wq, Wk, Wv, Wt);
    qkv_kernel<<<BB * SS / 64, 256, 0, stream>>>(x, Wt, bq, bk, bv, Q, K, Vt);
    flash_kernel<<<BB * 4 * (SS / 128), 256, 0, stream>>>(Q, K, Vt, Onorm, lse);
    merge_kernel<<<BB * SS * 8 / 256, 256, 0, stream>>>(Onorm, lse, out);
}

// Round 12
// 81.799 us; speedup vs baseline: 1.3365x; 1.0590x over previous
//
#include <hip/hip_runtime.h>
#include <math.h>

#define BB 8
#define SS 4096
#define EE 128
#define HH 64
#define NT 16   // KV tiles per flash block (split-K4: 1024 keys / 64)
#define LOG2E 1.44269504088896f

typedef _Float16 f16;
typedef __attribute__((ext_vector_type(8))) _Float16 f16x8;
typedef __attribute__((ext_vector_type(4))) float f32x4;
typedef __attribute__((ext_vector_type(16))) float f32x16;
typedef __attribute__((ext_vector_type(4))) unsigned int u32x4;

__device__ __forceinline__ unsigned int pk2h(float a, float b) {
    return __builtin_bit_cast(unsigned int, __builtin_amdgcn_cvt_pkrtz(a, b));
}

// async global->LDS DMA, 16 B per lane (linear LDS dest; swizzle is applied
// to the per-lane GLOBAL source address -- m173 pattern / rule #21).
__device__ __forceinline__ void async_copy16(void* lds, const void* g) {
    __builtin_amdgcn_global_load_lds(
        (const __attribute__((address_space(1))) void*)g,
        (__attribute__((address_space(3))) void*)lds, 16, 0, 0);
}

// ALL-WAVES buffer handoff: per-wave vmcnt(0)+lgkmcnt(0) then s_barrier.
// vmcnt is per-wave; the s_barrier is what makes every wave's DMA chunk
// visible to every reader (R7's race: dropping the barrier here).
__device__ __forceinline__ void vm_barrier() {
    asm volatile("s_waitcnt vmcnt(0) lgkmcnt(0)" ::: "memory");
    __builtin_amdgcn_s_barrier();
    __builtin_amdgcn_sched_barrier(0);
}

// ---------------- W transpose+convert setup ----------------
// Wt f16 [192 cols][128 e]: cols 0-63 = Wq*log2e, 64-127 = Wk, 128-191 = Wv.
__global__ __launch_bounds__(256) void wtrans_kernel(
    const float* __restrict__ Wq, const float* __restrict__ Wk,
    const float* __restrict__ Wv, f16* __restrict__ Wt)
{
    const int idx = blockIdx.x * 256 + threadIdx.x;
    if (idx >= 192 * 128) return;
    const int col = idx >> 7, e = idx & 127;
    const float v = (col < 64)  ? Wq[e * 64 + col] * LOG2E
                  : (col < 128) ? Wk[e * 64 + (col - 64)]
                                : Wv[e * 64 + (col - 128)];
    Wt[col * 128 + e] = (f16)v;
}

// ---------------- QKV projection: fp16 MFMA GEMM, 3-way split, no LDS ----------------
// grid 1536 = 512 row-tiles x 3 matrices (which = bid%3 -> Q/K/Vt).
// Each block: 64 rows x 64 cols of ONE output -> acc 16 VGPR, ~24 waves/CU.
// x re-read 3x but fully L3-resident. A-frags read directly from global x
// (coalesced). Q pre-scaled by log2e. Vt written with sigma-permuted key
// index (swap bits 2<->3 of low nibble) so flash PV frags are b128 reads.
__global__ __launch_bounds__(256) void qkv_kernel(
    const float* __restrict__ x, const f16* __restrict__ Wt,
    const float* __restrict__ bq, const float* __restrict__ bk,
    const float* __restrict__ bv,
    f16* __restrict__ Q, f16* __restrict__ K, f16* __restrict__ Vt)
{
    const int tid  = threadIdx.x;
    const int lane = tid & 63;
    const int wid  = tid >> 6;
    const int ln15 = lane & 15;
    const int lg   = lane >> 4;
    const int which   = blockIdx.x % 3;
    const int rowtile = blockIdx.x / 3;
    const long rowbase = (long)rowtile * 64;

    // A fragments: row = wid*16 + ln15, dim = s*32 + lg*8 + j
    f16x8 xa[4];
    {
        const float* xp = x + (rowbase + wid * 16 + ln15) * EE + lg * 8;
#pragma unroll
        for (int s = 0; s < 4; ++s) {
            const float4 u = *(const float4*)(xp + s * 32);
            const float4 v = *(const float4*)(xp + s * 32 + 4);
            const u32x4 w = {pk2h(u.x, u.y), pk2h(u.z, u.w),
                             pk2h(v.x, v.y), pk2h(v.z, v.w)};
            xa[s] = __builtin_bit_cast(f16x8, w);
        }
    }

    f32x4 acc[4];
#pragma unroll
    for (int ct = 0; ct < 4; ++ct) acc[ct] = (f32x4){0.f, 0.f, 0.f, 0.f};

#pragma unroll
    for (int ct = 0; ct < 4; ++ct) {
        const f16* wtp = Wt + ((which * 64 + ct * 16 + ln15) * 128) + lg * 8;
#pragma unroll
        for (int s = 0; s < 4; ++s) {
            const f16x8 wb = *(const f16x8*)(wtp + s * 32);
            acc[ct] = __builtin_amdgcn_mfma_f32_16x16x32_f16(xa[s], wb, acc[ct], 0, 0, 0);
        }
    }

    const long grow0 = rowbase + wid * 16 + 4 * lg;
    if (which == 0) {
#pragma unroll
        for (int ct = 0; ct < 4; ++ct) {
            const int col = ct * 16 + ln15;
            const float b = bq[col] * LOG2E;
#pragma unroll
            for (int r = 0; r < 4; ++r)
                Q[(grow0 + r) * HH + col] = (f16)(acc[ct][r] + b);
        }
    } else if (which == 1) {
#pragma unroll
        for (int ct = 0; ct < 4; ++ct) {
            const int col = ct * 16 + ln15;
            const float b = bk[col];
#pragma unroll
            for (int r = 0; r < 4; ++r)
                K[(grow0 + r) * HH + col] = (f16)(acc[ct][r] + b);
        }
    } else {
        const long batch = rowbase >> 12;
        // sigma-permuted key index: key&15 = 4*lg + r -> pos&15 = 8*(lg&1)+4*(lg>>1)+r
        const long inrow0 = (rowbase & 4095) + wid * 16;
        const long inrowP = inrow0 + 8 * (lg & 1) + 4 * (lg >> 1);
#pragma unroll
        for (int ct = 0; ct < 4; ++ct) {
            const int o = ct * 16 + ln15;
            const float b = bv[o];
            unsigned long long pk =
                (unsigned long long)pk2h(acc[ct][0] + b, acc[ct][1] + b) |
                ((unsigned long long)pk2h(acc[ct][2] + b, acc[ct][3] + b) << 32);
            *(unsigned long long*)(Vt + ((long)batch * HH + o) * SS + inrowP) = pk;
        }
    }
}

// ---------------- MFMA flash attention, 32x32, O^T, split-K4 (R8 proven) ----------------
// grid 1024 = 8 batch (XCD-affine) x 4 split x 32 qblk; 256 thr = 4 waves.
// Wave = 32 q rows (q = lane&31). KV tile = 64 keys, double-buffered LDS via
// global_load_lds DMA (pre-swizzled source). Swapped QK^T (32x32x16) puts q
// lane-local; P stays in REGISTERS (consistent-permutation trick) and the
// sigma-permuted Vt makes each PV A-frag ONE b128 LDS read. PV computes O^T
// so rescale/epilogue are lane-local. issue->compute->vm_barrier loop.
__global__ __launch_bounds__(256, 4) void flash_kernel(
    const f16* __restrict__ Q, const f16* __restrict__ K,
    const f16* __restrict__ Vt, f16* __restrict__ Onorm,
    float* __restrict__ lse)
{
    __shared__ __align__(16) short k_s[2][64 * HH];   // 2 x 8 KB
    __shared__ __align__(16) short v_s[2][64 * HH];   // 2 x 8 KB  [o][key-perm]

    const int tid  = threadIdx.x;
    const int lane = tid & 63;
    const int wid  = tid >> 6;
    const int q31  = lane & 31;
    const int h5   = lane >> 5;
    const int batch = blockIdx.x & 7;
    const int split = (blockIdx.x >> 3) & 3;
    const int qblk  = blockIdx.x >> 5;
    const int k0base = split * (SS / 4);

    // Q B-frags: col q = q31, k-slot 8h5+j at dim 16*step + 8*h5 + j
    f16x8 qf[4];
    {
        const long qrow = (long)batch * SS + qblk * 128 + wid * 32 + q31;
        const f16* qp = Q + qrow * HH + 8 * h5;
        qf[0] = *(const f16x8*)(qp);
        qf[1] = *(const f16x8*)(qp + 16);
        qf[2] = *(const f16x8*)(qp + 32);
        qf[3] = *(const f16x8*)(qp + 48);
    }

    f32x16 oacc0 = {0.f,0.f,0.f,0.f,0.f,0.f,0.f,0.f,0.f,0.f,0.f,0.f,0.f,0.f,0.f,0.f};
    f32x16 oacc1 = oacc0;           // O^T rows o (+32), col q = q31
    float m = -1e30f, l = 0.f;

    // ---- DMA staging geometry ----
    const int crow = lane >> 3;                       // 0..7
    const int ccs  = ((lane & 7) * 16) ^ (crow << 4); // swizzled col bytes
    const int row0 = wid * 16 + crow;                 // rows row0, row0+8
    const char* kgb = (const char*)(K + ((long)batch * SS + k0base) * HH);
    const char* vgb = (const char*)(Vt + (long)batch * HH * SS);
    const long koff = (long)row0 * 128 + ccs;
    const long voff = (long)row0 * (SS * 2) + k0base * 2 + ccs;

    auto issue = [&](int t, int b) __attribute__((always_inline)) {
        char* kl = (char*)k_s[b] + wid * 2048;
        char* vl = (char*)v_s[b] + wid * 2048;
        const char* kg = kgb + (long)t * (64 * 128) + koff;
        const char* vg = vgb + (long)t * 128 + voff;
        async_copy16(kl,        kg);
        async_copy16(kl + 1024, kg + 1024);            // rows +8
        async_copy16(vl,        vg);
        async_copy16(vl + 1024, vg + 8 * (SS * 2));    // rows +8
    };

    // compute one 64-key tile from buffer `cur` (literal 0/1 at call sites)
    auto compute = [&](int cur) __attribute__((always_inline)) {
        const char* ks = (const char*)k_s[cur];
        const char* vs = (const char*)v_s[cur];

        // ---- QK^T: S^T[key][q] = mfma(A=K rows, B=Q cols), log2 domain ----
        f32x16 s0 = {0.f,0.f,0.f,0.f,0.f,0.f,0.f,0.f,0.f,0.f,0.f,0.f,0.f,0.f,0.f,0.f};
        f32x16 s1 = s0;
        __builtin_amdgcn_s_setprio(1);
#pragma unroll
        for (int step = 0; step < 4; ++step) {
            const int cb = step * 32 + 16 * h5;
            const int r0 = q31;
            const f16x8 ka0 = *(const f16x8*)(ks + ((r0 * 128 + cb) ^ ((r0 & 7) << 4)));
            s0 = __builtin_amdgcn_mfma_f32_32x32x16_f16(ka0, qf[step], s0, 0, 0, 0);
            const int r1 = q31 + 32;
            const f16x8 ka1 = *(const f16x8*)(ks + ((r1 * 128 + cb) ^ ((r1 & 7) << 4)));
            s1 = __builtin_amdgcn_mfma_f32_32x32x16_f16(ka1, qf[step], s1, 0, 0, 0);
        }
        __builtin_amdgcn_s_setprio(0);

        // ---- online softmax (exp2 domain), q lane-local, defer-max ----
        float tm = s0[0];
#pragma unroll
        for (int i = 1; i < 16; ++i) tm = fmaxf(tm, s0[i]);
#pragma unroll
        for (int i = 0; i < 16; ++i) tm = fmaxf(tm, s1[i]);
        tm = fmaxf(tm, __shfl_xor(tm, 32));
        if (!__all(tm <= m + 11.5f)) {
            const float mn = fmaxf(m, tm);
            const float alpha = __builtin_amdgcn_exp2f(m - mn);
            l *= alpha;
            oacc0 *= alpha;              // lane-local: O^T col = q
            oacc1 *= alpha;
            m = mn;
        }

        unsigned int pk[16];
        float ps = 0.f;
#pragma unroll
        for (int i = 0; i < 8; ++i) {
            const float a = __builtin_amdgcn_exp2f(s0[2 * i] - m);
            const float b = __builtin_amdgcn_exp2f(s0[2 * i + 1] - m);
            ps += a + b;
            pk[i] = pk2h(a, b);
        }
#pragma unroll
        for (int i = 0; i < 8; ++i) {
            const float a = __builtin_amdgcn_exp2f(s1[2 * i] - m);
            const float b = __builtin_amdgcn_exp2f(s1[2 * i + 1] - m);
            ps += a + b;
            pk[8 + i] = pk2h(a, b);
        }
        ps += __shfl_xor(ps, 32);
        l += ps;

        // ---- O^T += V^T . P  (A = V^T single b128, sigma-permuted; B = P regs) ----
        __builtin_amdgcn_s_setprio(1);
#pragma unroll
        for (int mb = 0; mb < 4; ++mb) {
            const u32x4 pw = {pk[4 * mb], pk[4 * mb + 1], pk[4 * mb + 2], pk[4 * mb + 3]};
            const f16x8 pb = __builtin_bit_cast(f16x8, pw);
            const int cb = 32 * mb + 16 * h5;
#pragma unroll
            for (int oh = 0; oh < 2; ++oh) {
                const int row = q31 + 32 * oh;
                const f16x8 va = *(const f16x8*)(vs + ((row * 128 + cb) ^ ((row & 7) << 4)));
                if (oh == 0)
                    oacc0 = __builtin_amdgcn_mfma_f32_32x32x16_f16(va, pb, oacc0, 0, 0, 0);
                else
                    oacc1 = __builtin_amdgcn_mfma_f32_32x32x16_f16(va, pb, oacc1, 0, 0, 0);
            }
        }
        __builtin_amdgcn_s_setprio(0);
    };

    // prologue: DMA tile 0 into buf0, drain, sync
    issue(0, 0);
    vm_barrier();

    for (int t = 0; t < NT; t += 2) {
        issue(t + 1, 1);                 // DMA next tile while computing
        compute(0);
        vm_barrier();                    // t+1 loads had full compute to land
        if (t + 2 < NT) issue(t + 2, 0);
        compute(1);
        vm_barrier();
    }

    // epilogue: normalized f16 partials (O^T scatter) + log2-LSE
    const float linv = 1.0f / l;
    const long tok = (long)split * (BB * SS) + (long)batch * SS + qblk * 128 + wid * 32 + q31;
    f16* ob = Onorm + tok * HH;
#pragma unroll
    for (int i = 0; i < 16; ++i) {
        const int od = (i & 3) + 8 * (i >> 2) + 4 * h5;
        ob[od]      = (f16)(oacc0[i] * linv);
        ob[od + 32] = (f16)(oacc1[i] * linv);
    }
    if (h5 == 0)
        lse[tok] = m + __builtin_amdgcn_logf(l);
}

// ---------------- split-K merge (log2-LSE weighted) ----------------
__global__ __launch_bounds__(256) void merge_kernel(
    const f16* __restrict__ Onorm, const float* __restrict__ lse,
    float* __restrict__ Out)
{
    const int gid = blockIdx.x * 256 + threadIdx.x;   // 32768 rows x 8 col-groups
    const long row = gid >> 3;
    const int c0 = (gid & 7) * 8;
    const long NR = (long)BB * SS;

    float ls[4];
#pragma unroll
    for (int i = 0; i < 4; ++i) ls[i] = lse[i * NR + row];
    const float M = fmaxf(fmaxf(ls[0], ls[1]), fmaxf(ls[2], ls[3]));
    float g[4], denom = 0.f;
#pragma unroll
    for (int i = 0; i < 4; ++i) { g[i] = __builtin_amdgcn_exp2f(ls[i] - M); denom += g[i]; }
    const float inv = 1.0f / denom;

    float acc[8];
#pragma unroll
    for (int j = 0; j < 8; ++j) acc[j] = 0.f;
#pragma unroll
    for (int i = 0; i < 4; ++i) {
        const f16x8 o = *(const f16x8*)(Onorm + (i * NR + row) * HH + c0);
#pragma unroll
        for (int j = 0; j < 8; ++j) acc[j] = fmaf(g[i], (float)o[j], acc[j]);
    }
    float4 r0, r1;
    r0.x = acc[0] * inv; r0.y = acc[1] * inv; r0.z = acc[2] * inv; r0.w = acc[3] * inv;
    r1.x = acc[4] * inv; r1.y = acc[5] * inv; r1.z = acc[6] * inv; r1.w = acc[7] * inv;
    float4* dst = (float4*)(Out + row * HH + c0);
    dst[0] = r0;
    dst[1] = r1;
}

extern "C" void kernel_launch(void* const* d_in, const int* in_sizes, int n_in,
                              void* d_out, int out_size, void* d_ws, size_t ws_size,
                              hipStream_t stream) {
    const float* x  = (const float*)d_in[0];
    const float* Wq = (const float*)d_in[1];
    const float* bq = (const float*)d_in[2];
    const float* Wk = (const float*)d_in[3];
    const float* bk = (const float*)d_in[4];
    const float* Wv = (const float*)d_in[5];
    const float* bv = (const float*)d_in[6];
    float* out = (float*)d_out;

    // ws: Q f16 4MB | K f16 4MB | Vt f16 4MB | Wt 48KB | Onorm f16 16MB | lse f32 512KB
    const size_t NTOK = (size_t)BB * SS;
    f16* Q  = (f16*)d_ws;
    f16* K  = Q + NTOK * HH;
    f16* Vt = K + NTOK * HH;
    f16* Wt = Vt + NTOK * HH;
    f16* Onorm = Wt + 192 * 128;
    float* lse = (float*)(Onorm + 4 * NTOK * HH);

    wtrans_kernel<<<96, 256, 0, stream>>>(Wq, Wk, Wv, Wt);
    qkv_kernel<<<3 * (BB * SS / 64), 256, 0, stream>>>(x, Wt, bq, bk, bv, Q, K, Vt);
    flash_kernel<<<BB * 4 * (SS / 128), 256, 0, stream>>>(Q, K, Vt, Onorm, lse);
    merge_kernel<<<BB * SS * 8 / 256, 256, 0, stream>>>(Onorm, lse, out);
}